// Round 1
// baseline (898.134 us; speedup 1.0000x reference)
//
#include <hip/hip_runtime.h>

#define TPB 256

// ---------------- degree / CSR build ----------------

__global__ void k_zero_deg(unsigned int* __restrict__ deg, int n) {
  int i = blockIdx.x * blockDim.x + threadIdx.x;
  if (i < n) deg[i] = 0u;
}

__global__ void k_hist(const int* __restrict__ dst, unsigned int* __restrict__ deg, int E) {
  int e = blockIdx.x * blockDim.x + threadIdx.x;
  if (e < E) atomicAdd(&deg[dst[e]], 1u);
}

// per-block exclusive scan of deg -> offs (partial), block totals -> btot
__global__ void k_scan1(const unsigned int* __restrict__ deg, int* __restrict__ offs,
                        int* __restrict__ btot, int n) {
  __shared__ int s[TPB];
  int t = threadIdx.x;
  int i = blockIdx.x * TPB + t;
  int v = (i < n) ? (int)deg[i] : 0;
  s[t] = v;
  __syncthreads();
  for (int d = 1; d < TPB; d <<= 1) {
    int u = (t >= d) ? s[t - d] : 0;
    __syncthreads();
    s[t] += u;
    __syncthreads();
  }
  if (i < n) offs[i] = s[t] - v;            // exclusive within block
  if (t == TPB - 1) btot[blockIdx.x] = s[t];
}

// single-block exclusive scan of block totals (nb <= 512)
__global__ void k_scan2(int* __restrict__ btot, int nb) {
  __shared__ int s[512];
  int t = threadIdx.x;
  int v = (t < nb) ? btot[t] : 0;
  s[t] = v;
  __syncthreads();
  for (int d = 1; d < 512; d <<= 1) {
    int u = (t >= d) ? s[t - d] : 0;
    __syncthreads();
    s[t] += u;
    __syncthreads();
  }
  if (t < nb) btot[t] = s[t] - v;           // exclusive
}

// finalize offsets, copy cursor, compute dis = 1/sqrt(deg+1)  (+1 = self loop)
__global__ void k_scan3(int* __restrict__ offs, const int* __restrict__ btot,
                        const unsigned int* __restrict__ deg,
                        int* __restrict__ cursor, float* __restrict__ dis,
                        int n, int E) {
  int i = blockIdx.x * blockDim.x + threadIdx.x;
  if (i < n) {
    int o = offs[i] + btot[i >> 8];
    offs[i] = o;
    cursor[i] = o;
    dis[i] = 1.0f / sqrtf((float)(deg[i] + 1u));
  }
  if (i == 0) offs[n] = E;
}

__global__ void k_place(const int* __restrict__ src, const int* __restrict__ dst,
                        int* __restrict__ cursor, int* __restrict__ csr, int E) {
  int e = blockIdx.x * blockDim.x + threadIdx.x;
  if (e < E) {
    int p = atomicAdd(&cursor[dst[e]], 1);
    csr[p] = src[e];
  }
}

// ---------------- layer 1 GEMM: hs[i] = dis[i] * (x[i] @ W1) ----------------
// wave-per-node; each lane owns W1 rows [lane*8, lane*8+8) in 128 VGPRs.
__global__ __launch_bounds__(256) void k_gemm1(
    const float* __restrict__ x, const float* __restrict__ W1,
    const float* __restrict__ dis, float* __restrict__ hs, int n, int nwaves) {
  const int lane = threadIdx.x & 63;
  const int wave = blockIdx.x * 4 + (threadIdx.x >> 6);

  float w[8][16];
  #pragma unroll
  for (int m = 0; m < 8; ++m) {
    #pragma unroll
    for (int q = 0; q < 4; ++q) {
      float4 t = *reinterpret_cast<const float4*>(W1 + (lane * 8 + m) * 16 + q * 4);
      w[m][q * 4 + 0] = t.x; w[m][q * 4 + 1] = t.y;
      w[m][q * 4 + 2] = t.z; w[m][q * 4 + 3] = t.w;
    }
  }
  // exchange-halves reduction leaves lane l owning column brev4(l&15)
  const int c_out = ((lane & 1) << 3) | ((lane & 2) << 1) | ((lane & 4) >> 1) | ((lane & 8) >> 3);

  for (int i = wave; i < n; i += nwaves) {
    const float4* xp = reinterpret_cast<const float4*>(x + (size_t)i * 512);
    float4 a = xp[lane * 2], b = xp[lane * 2 + 1];
    float xv[8] = {a.x, a.y, a.z, a.w, b.x, b.y, b.z, b.w};

    float acc[16];
    #pragma unroll
    for (int c = 0; c < 16; ++c) acc[c] = 0.f;
    #pragma unroll
    for (int m = 0; m < 8; ++m) {
      #pragma unroll
      for (int c = 0; c < 16; ++c) acc[c] = fmaf(xv[m], w[m][c], acc[c]);
    }

    // fold 16 values -> 1 while summing across lanes: masks 1,2,4,8 then 16,32
    {
      const bool hi = (lane & 1) != 0;
      #pragma unroll
      for (int v = 0; v < 8; ++v) {
        float send = hi ? acc[v] : acc[v + 8];
        float rcv = __shfl_xor(send, 1);
        acc[v] = (hi ? acc[v + 8] : acc[v]) + rcv;
      }
    }
    {
      const bool hi = (lane & 2) != 0;
      #pragma unroll
      for (int v = 0; v < 4; ++v) {
        float send = hi ? acc[v] : acc[v + 4];
        float rcv = __shfl_xor(send, 2);
        acc[v] = (hi ? acc[v + 4] : acc[v]) + rcv;
      }
    }
    {
      const bool hi = (lane & 4) != 0;
      #pragma unroll
      for (int v = 0; v < 2; ++v) {
        float send = hi ? acc[v] : acc[v + 2];
        float rcv = __shfl_xor(send, 4);
        acc[v] = (hi ? acc[v + 2] : acc[v]) + rcv;
      }
    }
    {
      const bool hi = (lane & 8) != 0;
      float send = hi ? acc[0] : acc[1];
      float rcv = __shfl_xor(send, 8);
      acc[0] = (hi ? acc[1] : acc[0]) + rcv;
    }
    float vsum = acc[0];
    vsum += __shfl_xor(vsum, 16);
    vsum += __shfl_xor(vsum, 32);

    if (lane < 16) hs[(size_t)i * 16 + c_out] = dis[i] * vsum;
  }
}

// ---------------- layer 1 aggregate + ELU + layer-2 prescale ----------------
// wave-per-dst-node: 16 cols x 4 edge slots. h1s[i] = dis[i]*elu(dis[i]*agg + b1)
__global__ __launch_bounds__(256) void k_agg1(
    const int* __restrict__ offs, const int* __restrict__ csr,
    const float* __restrict__ hs, const float* __restrict__ dis,
    const float* __restrict__ b1, float* __restrict__ h1s, int n) {
  int wave = blockIdx.x * 4 + (threadIdx.x >> 6);
  if (wave >= n) return;
  int lane = threadIdx.x & 63;
  int c = lane & 15, r = lane >> 4;
  int beg = offs[wave], end = offs[wave + 1];
  float acc = 0.f;
  for (int k = beg + r; k < end; k += 4)
    acc += hs[(size_t)csr[k] * 16 + c];
  acc += __shfl_xor(acc, 16);
  acc += __shfl_xor(acc, 32);
  acc += hs[(size_t)wave * 16 + c];          // self loop
  float di = dis[wave];
  float o = fmaf(di, acc, b1[c]);
  float h1 = o > 0.f ? o : expm1f(o);        // elu, alpha=1
  if (r == 0) h1s[(size_t)wave * 16 + c] = di * h1;
}

// ---------------- layer 2 aggregate + 16x16 GEMM + bias + log_softmax ------
__global__ __launch_bounds__(256) void k_agg2(
    const int* __restrict__ offs, const int* __restrict__ csr,
    const float* __restrict__ h1s, const float* __restrict__ dis,
    const float* __restrict__ W2, const float* __restrict__ b2,
    float* __restrict__ out, int n) {
  __shared__ float w2s[256];
  w2s[threadIdx.x] = W2[threadIdx.x];
  __syncthreads();
  int wave = blockIdx.x * 4 + (threadIdx.x >> 6);
  if (wave >= n) return;
  int lane = threadIdx.x & 63;
  int c = lane & 15, r = lane >> 4;
  int beg = offs[wave], end = offs[wave + 1];
  float acc = 0.f;
  for (int k = beg + r; k < end; k += 4)
    acc += h1s[(size_t)csr[k] * 16 + c];
  acc += __shfl_xor(acc, 16);
  acc += __shfl_xor(acc, 32);
  acc += h1s[(size_t)wave * 16 + c];         // self loop
  float di = dis[wave];
  float dot = 0.f;
  #pragma unroll
  for (int k = 0; k < 16; ++k) {
    float vk = __shfl(acc, k, 16);           // broadcast feature k within 16-group
    dot = fmaf(vk, w2s[k * 16 + c], dot);
  }
  float o = fmaf(di, dot, b2[c]);
  // log_softmax over the 16 class lanes
  float m = o;
  m = fmaxf(m, __shfl_xor(m, 1));
  m = fmaxf(m, __shfl_xor(m, 2));
  m = fmaxf(m, __shfl_xor(m, 4));
  m = fmaxf(m, __shfl_xor(m, 8));
  float ex = expf(o - m);
  float ssum = ex;
  ssum += __shfl_xor(ssum, 1);
  ssum += __shfl_xor(ssum, 2);
  ssum += __shfl_xor(ssum, 4);
  ssum += __shfl_xor(ssum, 8);
  if (r == 0) out[(size_t)wave * 16 + c] = o - m - logf(ssum);
}

// ---------------- launch ----------------

extern "C" void kernel_launch(void* const* d_in, const int* in_sizes, int n_in,
                              void* d_out, int out_size, void* d_ws, size_t ws_size,
                              hipStream_t stream) {
  const float* x  = (const float*)d_in[0];
  const int*   ei = (const int*)d_in[1];
  const float* W1 = (const float*)d_in[2];
  const float* b1 = (const float*)d_in[3];
  const float* W2 = (const float*)d_in[4];
  const float* b2 = (const float*)d_in[5];
  float* out = (float*)d_out;

  const int n = in_sizes[0] / 512;
  const int E = in_sizes[1] / 2;
  const int* src = ei;
  const int* dst = ei + E;

  char* ws = (char*)d_ws;
  size_t off = 0;
  auto alloc = [&](size_t bytes) -> void* {
    void* p = (void*)(ws + off);
    off += (bytes + 255) & ~(size_t)255;
    return p;
  };
  unsigned int* deg = (unsigned int*)alloc((size_t)n * 4);
  int*   offs   = (int*)alloc((size_t)(n + 1) * 4);
  int*   cursor = (int*)alloc((size_t)n * 4);
  int*   btot   = (int*)alloc(512 * 4);
  float* dis    = (float*)alloc((size_t)n * 4);
  int*   csr    = (int*)alloc((size_t)E * 4);
  float* hs     = (float*)alloc((size_t)n * 16 * 4);
  float* h1s    = (float*)alloc((size_t)n * 16 * 4);
  (void)ws_size; (void)n_in; (void)out_size;

  const int nb = (n + TPB - 1) / TPB;   // 391 blocks for n=100000
  const int eb = (E + TPB - 1) / TPB;
  const int ab = (n + 3) / 4;           // 4 waves (nodes) per block

  k_zero_deg<<<nb, TPB, 0, stream>>>(deg, n);
  k_hist    <<<eb, TPB, 0, stream>>>(dst, deg, E);
  k_scan1   <<<nb, TPB, 0, stream>>>(deg, offs, btot, n);
  k_scan2   <<<1, 512, 0, stream>>>(btot, nb);
  k_scan3   <<<nb, TPB, 0, stream>>>(offs, btot, deg, cursor, dis, n, E);
  k_place   <<<eb, TPB, 0, stream>>>(src, dst, cursor, csr, E);
  k_gemm1   <<<2048, TPB, 0, stream>>>(x, W1, dis, hs, n, 2048 * 4);
  k_agg1    <<<ab, TPB, 0, stream>>>(offs, csr, hs, dis, b1, h1s, n);
  k_agg2    <<<ab, TPB, 0, stream>>>(offs, csr, h1s, dis, W2, b2, out, n);
}